// Round 6
// baseline (207.464 us; speedup 1.0000x reference)
//
#include <hip/hip_runtime.h>
#include <math.h>

#define BB 2
#define TT 2048
#define EE 1024
#define HH 16
#define DD 64
#define MM (BB*TT)   // 4096
#define KK EE        // 1024

typedef short bf16x8 __attribute__((ext_vector_type(8)));
typedef float f32x4  __attribute__((ext_vector_type(4)));
typedef float f32x16 __attribute__((ext_vector_type(16)));
typedef unsigned int u32x4 __attribute__((ext_vector_type(4)));

// round-to-nearest-even fp32 -> bf16 (as ushort)
__device__ __forceinline__ unsigned short f2bf(float f) {
  unsigned int u = __float_as_uint(f);
  u = (u + 0x7FFFu + ((u >> 16) & 1u)) >> 16;
  return (unsigned short)u;
}

// packed RNE fp32x2 -> bf16x2 (low = lo)
__device__ __forceinline__ unsigned int cvtpk(float lo, float hi) {
  unsigned int r;
  asm("v_cvt_pk_bf16_f32 %0, %1, %2" : "=v"(r) : "v"(lo), "v"(hi));
  return r;
}

// (a,b) -> a = {a_lo, b_lo}, b = {a_hi, b_hi}  (32-lane half swap)
__device__ __forceinline__ void plswap(unsigned int &a, unsigned int &b) {
  asm("v_permlane32_swap_b32 %0, %1" : "+v"(a), "+v"(b));
}

// async global->LDS DMA, 16B per lane, LDS dest = wave-uniform base + lane*16
__device__ __forceinline__ void async16(const void* g, void* l) {
  __builtin_amdgcn_global_load_lds(
      (const __attribute__((address_space(1))) unsigned int*)g,
      (__attribute__((address_space(3))) unsigned int*)l, 16, 0, 0);
}

// ---------------------------------------------------------------------------
// fp32 -> bf16 convert for x and the 4 weight matrices (Wq/Wk/Wv concatenated
// row-wise into one [3072 x 1024] buffer for the fused QKV GEMM).
// ---------------------------------------------------------------------------
__global__ __launch_bounds__(256) void to_bf16(
    const float* __restrict__ x,  const float* __restrict__ wq,
    const float* __restrict__ wk, const float* __restrict__ wv,
    const float* __restrict__ wo,
    unsigned short* __restrict__ xh, unsigned short* __restrict__ wcat,
    unsigned short* __restrict__ woh)
{
  int c = blockIdx.x * 256 + threadIdx.x;
  const float* src; unsigned short* dst; int off;
  if (c < 1048576) { src = x; dst = xh; off = c; }
  else {
    int r = c - 1048576;
    int w = r >> 18;                 // 262144 chunks per W
    off = r & 262143;
    if      (w == 0) { src = wq; dst = wcat; }
    else if (w == 1) { src = wk; dst = wcat + (1 << 20); }
    else if (w == 2) { src = wv; dst = wcat + (2 << 20); }
    else             { src = wo; dst = woh; }
  }
  float4 v = ((const float4*)src)[off];
  ushort4 h;
  h.x = f2bf(v.x); h.y = f2bf(v.y); h.z = f2bf(v.z); h.w = f2bf(v.w);
  ((ushort4*)dst)[off] = h;
}

// ---------------------------------------------------------------------------
// bf16 MFMA GEMM — m97 structure: 256 threads / 4 waves, tile 128x128, wave
// owns a 64x64 quadrant (acc[4][4], 16 MFMAs : 8 ds_read_b128 per BK=32),
// width-16 global_load_lds staging, double-buffered LDS, 2 barriers/K-step.
// (Replaces the 8-wave 32x64-per-wave decomposition: 8 MFMA : 6 ds_read was
// the ~330 TF-class ratio; this one measured 912 TF at 4096^3 in learn_hip.)
// MODE 0: fused QKV, N=3072, region by n0: Q (*qscale) / K -> bf16 [b,h,t,d];
//         V -> bf16 [b,h,d,t]. Epilogue bounces C through LDS for 16B stores.
// MODE 2: fp32 out [m,EE], direct dword stores.
// ---------------------------------------------------------------------------
template<int MODE>
__global__ __launch_bounds__(256) void gemm_bf16(
    const unsigned short* __restrict__ A, const unsigned short* __restrict__ B,
    const float* __restrict__ b0p, const float* __restrict__ b1p,
    const float* __restrict__ b2p,
    unsigned short* __restrict__ oq, unsigned short* __restrict__ ok,
    unsigned short* __restrict__ ov, float* __restrict__ ofp, float qscale)
{
  // dbuf: A 2*4096 + B 2*4096 = 16384 ushorts; Cs alias needs 17408
  __shared__ unsigned short S[17408];

  const int tid  = threadIdx.x;
  const int lane = tid & 63;
  const int wv   = tid >> 6;                   // 0..3
  const int col  = lane & 15;
  const int quad = lane >> 4;
  const int wm = (wv & 1) * 64;
  const int wn = (wv >> 1) * 64;
  const int m0 = blockIdx.x * 128;
  const int n0 = blockIdx.y * 128;

  const int srow = lane >> 2;                                // 16 rows/call
  const int sw16 = (((lane & 3) ^ ((lane >> 2) & 3)) << 3);  // ushort units
  const int fswA = ((quad ^ (col & 3)) << 3);                // frag slot

  auto stage = [&](int kt, int b) {
#pragma unroll
    for (int s = 0; s < 4; ++s) {
      const int t = wv * 4 + s;                // 0..15
      const unsigned short* src; int rb, g0, loff;
      if (t < 8) { src = A; rb = t * 16;       g0 = m0; loff = b * 4096; }
      else       { src = B; rb = (t - 8) * 16; g0 = n0; loff = 8192 + b * 4096; }
      async16(src + (size_t)(g0 + rb + srow) * KK + kt + sw16,
              S + loff + rb * 32);
    }
  };

  f32x4 acc[4][4];
  const f32x4 z = {0.f, 0.f, 0.f, 0.f};
#pragma unroll
  for (int i = 0; i < 4; ++i)
#pragma unroll
    for (int j = 0; j < 4; ++j) acc[i][j] = z;

  stage(0, 0);
  __syncthreads();

  for (int kt = 0; kt < KK; kt += 32) {
    const int buf = (kt >> 5) & 1;
    if (kt + 32 < KK) stage(kt + 32, buf ^ 1);

    const unsigned short* Asb = S + buf * 4096;
    const unsigned short* Bsb = S + 8192 + buf * 4096;
    bf16x8 bfr[4];
#pragma unroll
    for (int j = 0; j < 4; ++j)
      bfr[j] = *(const bf16x8*)(Bsb + (wn + j * 16 + col) * 32 + fswA);
#pragma unroll
    for (int i = 0; i < 4; ++i) {
      bf16x8 af = *(const bf16x8*)(Asb + (wm + i * 16 + col) * 32 + fswA);
#pragma unroll
      for (int j = 0; j < 4; ++j)
        acc[i][j] = __builtin_amdgcn_mfma_f32_16x16x32_bf16(af, bfr[j], acc[i][j], 0, 0, 0);
    }
    __syncthreads();
  }

  // Epilogue. C/D: row = quad*4+r, col = lane&15 per 16x16 tile.
  unsigned short* Cs = S;
  if (MODE == 0) {
    const int region = n0 >> 10;   // block-uniform: 0=Q, 1=K, 2=V
    const float* bias = (region == 0) ? b0p : (region == 1) ? b1p : b2p;
    const float scl = (region == 0) ? qscale : 1.0f;
    const int nlbase = n0 & 1023;
    const int h0 = nlbase >> 6;
    const int b = m0 >> 11, t0 = m0 & (TT - 1);
    if (region < 2) {
      // Cs[m][n] (stride 136): scalar bf16 writes, coalesced row reads.
#pragma unroll
      for (int i = 0; i < 4; ++i)
#pragma unroll
        for (int j = 0; j < 4; ++j) {
          const int nt = wn + j * 16 + col;
          const float bs = bias[nlbase + nt];
#pragma unroll
          for (int r = 0; r < 4; ++r) {
            const int mt = wm + i * 16 + quad * 4 + r;
            Cs[mt * 136 + nt] = f2bf((acc[i][j][r] + bs) * scl);
          }
        }
      __syncthreads();
      unsigned short* dst = (region == 0) ? oq : ok;
#pragma unroll
      for (int s = 0; s < 8; ++s) {
        const int u = s * 256 + tid;          // 2048 units: 128m x 2h x 8ch
        const int mt = u >> 4, hs = (u >> 3) & 1, ch = u & 7;
        const size_t g = ((size_t)(b * HH + h0 + hs) * TT + t0 + mt) * DD + ch * 8;
        *(uint4*)(dst + g) = *(const uint4*)(Cs + mt * 136 + hs * 64 + ch * 8);
      }
    } else {
      // V: Cs[n][m] (stride 136): packed b64 writes, coalesced row reads.
#pragma unroll
      for (int i = 0; i < 4; ++i)
#pragma unroll
        for (int j = 0; j < 4; ++j) {
          const int nt = wn + j * 16 + col;
          const float bs = bias[nlbase + nt];
          ushort4 pk;
          pk.x = f2bf(acc[i][j][0] + bs);
          pk.y = f2bf(acc[i][j][1] + bs);
          pk.z = f2bf(acc[i][j][2] + bs);
          pk.w = f2bf(acc[i][j][3] + bs);
          *(ushort4*)(Cs + nt * 136 + wm + i * 16 + quad * 4) = pk;
        }
      __syncthreads();
#pragma unroll
      for (int s = 0; s < 8; ++s) {
        const int u = s * 256 + tid;          // 2048 units: 128n x 16ch(m)
        const int nt = u >> 4, ch = u & 15;
        const int d = nt & 63, hs = nt >> 6;
        const size_t g = ((size_t)(b * HH + h0 + hs) * DD + d) * TT + t0 + ch * 8;
        *(uint4*)(ov + g) = *(const uint4*)(Cs + nt * 136 + ch * 8);
      }
    }
  } else {
#pragma unroll
    for (int i = 0; i < 4; ++i) {
#pragma unroll
      for (int j = 0; j < 4; ++j) {
        const int n = n0 + wn + j * 16 + col;
        const float bs = b0p[n];
#pragma unroll
        for (int r = 0; r < 4; ++r) {
          const int m = m0 + wm + i * 16 + quad * 4 + r;
          ofp[(size_t)m * EE + n] = acc[i][j][r] + bs;
        }
      }
    }
  }
}

// ---------------------------------------------------------------------------
// MFMA flash attention, 512 threads / 8 waves, 32x32x16 MFMA.
// Wave grid: wq = wv&3 owns 32 q-rows, wk2 = wv>>2 owns a 32-k half of each
// 64-k tile (O partials merged in epilogue). Max-free softmax (Q pre-scaled
// by log2e/8, p = 2^s). S computed transposed (A=K, B=Q) so each lane holds
// P for one q-row; PV A-frags formed IN REGISTERS via v_cvt_pk_bf16_f32 +
// v_permlane32_swap_b32 (T12) — no P LDS roundtrip. QK MFMAs accumulate
// DIRECTLY into the alternating sacc/nsacc register set (first MFMA takes
// C = zero) — no init movs, no 16-reg ping-pong copy (prev round: VALUBusy
// 39% with ~175 VALU/tile/wave vs ~40 algorithmic; acc copies were most of
// the excess). K/V quad-buffered, 2-ahead prefetch, counted vmcnt(2), one
// barrier per tile.
// ---------------------------------------------------------------------------
__global__ __launch_bounds__(512, 4) void flash_mfma(
    const unsigned short* __restrict__ Qb, const unsigned short* __restrict__ Kb,
    const unsigned short* __restrict__ Vtb, unsigned short* __restrict__ ctx)
{
  __shared__ unsigned short Qs[128 * 64];      // 16 KB (lred/linv at epilogue)
  __shared__ unsigned short Ks[4][64 * 64];    // 32 KB quad-buffered
  __shared__ unsigned short Vts[4][64 * 64];   // 32 KB quad-buffered

  const int tid  = threadIdx.x;
  const int lane = tid & 63;
  const int wv   = tid >> 6;                   // 0..7
  const int lq   = lane & 31;                  // q- or k-local index
  const int hf   = lane >> 5;                  // lane half
  const int wq   = wv & 3;                     // q-block 32*wq
  const int wk2  = wv >> 2;                    // k-half 32*wk2
  const int gid  = blockIdx.x;
  const int bh   = gid & 31;                   // XCD = gid%8 = bh%8
  const int q0   = (gid >> 5) * 128;

  const unsigned short* Qg = Qb  + (size_t)bh * TT * DD;
  const unsigned short* Kg = Kb  + (size_t)bh * TT * DD;
  const unsigned short* Vg = Vtb + (size_t)bh * DD * TT;

  const int srow = lane >> 3;                                // 8 rows/call
  const int sw16 = (((lane & 7) ^ ((lane >> 3) & 7)) << 3);  // ushort units

  // ---- staging (waves 0-3: K, waves 4-7: V^T) ----------------------------
  const int rbK = wq * 16;
  const bool isK = (wv < 4);
  const unsigned short* g0 =
      (isK ? Kg + (size_t)(rbK + srow) * DD : Vg + (size_t)(rbK + srow) * TT) + sw16;
  const unsigned short* g1 = g0 + (isK ? 8 * DD : 8 * TT);
  unsigned short* l0 = (isK ? &Ks[0][0] : &Vts[0][0]) + rbK * 64;
  unsigned short* l1 = l0 + 8 * 64;
  const int gstep = isK ? 64 * DD : 64;        // ushorts per k-tile advance

  auto stage_kv = [&](int ti, int slot) {
    const size_t go = (size_t)ti * gstep;
    async16(g0 + go, l0 + slot * 4096);
    async16(g1 + go, l1 + slot * 4096);
  };

  // ---- loop-invariant fragment byte offsets (XOR chunk-swizzled) ---------
  int koff[4], voff[2][2];
#pragma unroll
  for (int s = 0; s < 4; ++s)
    koff[s] = ((wk2 * 32 + lq) * 64 + (((2 * s + hf) ^ (lane & 7)) << 3)) * 2;
#pragma unroll
  for (int m = 0; m < 2; ++m)
#pragma unroll
    for (int sg = 0; sg < 2; ++sg)
      voff[m][sg] = ((m * 32 + lq) * 64 +
                     (((wk2 * 4 + 2 * sg + hf) ^ (lane & 7)) << 3)) * 2;

  // stage Q (128x64) + K/V tiles 0,1
#pragma unroll
  for (int s = 0; s < 2; ++s) {
    const int rb = wv * 16 + s * 8;
    async16(Qg + (size_t)(q0 + rb + srow) * DD + sw16, &Qs[rb * 64]);
  }
  stage_kv(0, 0);
  stage_kv(1, 1);
  __syncthreads();                             // Q + KV0 + KV1 visible

  // hoist Q fragments (B-operand of S^T): Q[q0+wq*32+lq][16s+8hf+i]
  bf16x8 aq[4];
#pragma unroll
  for (int s = 0; s < 4; ++s)
    aq[s] = *(const bf16x8*)(Qs + (wq * 32 + lq) * 64 +
                             (((2 * s + hf) ^ (lane & 7)) << 3));

  const f32x16 z16 = {0.f,0.f,0.f,0.f,0.f,0.f,0.f,0.f,
                      0.f,0.f,0.f,0.f,0.f,0.f,0.f,0.f};
  f32x16 o_acc[2], sacc, nsacc;
  o_acc[0] = z16; o_acc[1] = z16;
  float lpart = 0.f;

  // prologue QK(0): sacc[r] = S^T[k = wk2*32 + (r&3)+8*(r>>2)+4hf][q = lq]
  {
    const char* Kp = (const char*)&Ks[0][0];
    bf16x8 ak = *(const bf16x8*)(Kp + koff[0]);
    sacc = __builtin_amdgcn_mfma_f32_32x32x16_bf16(ak, aq[0], z16, 0, 0, 0);
#pragma unroll
    for (int s = 1; s < 4; ++s) {
      ak = *(const bf16x8*)(Kp + koff[s]);
      sacc = __builtin_amdgcn_mfma_f32_32x32x16_bf16(ak, aq[s], sacc, 0, 0, 0);
    }
  }

#define BODY(T, S0, S1, S2, DOSTAGE, DOQK, VMC, SIN, SOUT) do {               \
    if (DOSTAGE) stage_kv((T) + 2, S2);                                       \
    asm volatile("s_waitcnt vmcnt(" #VMC ")" ::: "memory");                   \
    __builtin_amdgcn_sched_barrier(0);                                        \
    __builtin_amdgcn_s_barrier();                                             \
    __builtin_amdgcn_sched_barrier(0);                                        \
    bf16x8 pa0, pa1;                                                          \
    {  /* softmax + in-register P A-frag (k-local 0..15 of wave's half) */    \
      float e0 = __builtin_amdgcn_exp2f(SIN[0]);                              \
      float e1 = __builtin_amdgcn_exp2f(SIN[1]);                              \
      float e2 = __builtin_amdgcn_exp2f(SIN[2]);                              \
      float e3 = __builtin_amdgcn_exp2f(SIN[3]);                              \
      float e4 = __builtin_amdgcn_exp2f(SIN[4]);                              \
      float e5 = __builtin_amdgcn_exp2f(SIN[5]);                              \
      float e6 = __builtin_amdgcn_exp2f(SIN[6]);                              \
      float e7 = __builtin_amdgcn_exp2f(SIN[7]);                              \
      lpart += ((e0 + e1) + (e2 + e3)) + ((e4 + e5) + (e6 + e7));             \
      unsigned int a0 = cvtpk(e0, e1), b0 = cvtpk(e4, e5);                    \
      unsigned int a1 = cvtpk(e2, e3), b1 = cvtpk(e6, e7);                    \
      plswap(a0, b0); plswap(a1, b1);                                         \
      u32x4 w = {a0, a1, b0, b1};                                             \
      pa0 = __builtin_bit_cast(bf16x8, w);                                    \
    }                                                                         \
    {  /* k-local 16..31 */                                                   \
      float e0 = __builtin_amdgcn_exp2f(SIN[8]);                              \
      float e1 = __builtin_amdgcn_exp2f(SIN[9]);                              \
      float e2 = __builtin_amdgcn_exp2f(SIN[10]);                             \
      float e3 = __builtin_amdgcn_exp2f(SIN[11]);                             \
      float e4 = __builtin_amdgcn_exp2f(SIN[12]);                             \
      float e5 = __builtin_amdgcn_exp2f(SIN[13]);                             \
      float e6 = __builtin_amdgcn_exp2f(SIN[14]);                             \
      float e7 = __builtin_amdgcn_exp2f(SIN[15]);                             \
      lpart += ((e0 + e1) + (e2 + e3)) + ((e4 + e5) + (e6 + e7));             \
      unsigned int a0 = cvtpk(e0, e1), b0 = cvtpk(e4, e5);                    \
      unsigned int a1 = cvtpk(e2, e3), b1 = cvtpk(e6, e7);                    \
      plswap(a0, b0); plswap(a1, b1);                                         \
      u32x4 w = {a0, a1, b0, b1};                                             \
      pa1 = __builtin_bit_cast(bf16x8, w);                                    \
    }                                                                         \
    __builtin_amdgcn_s_setprio(1);                                            \
    if (DOQK) {  /* QK(t+1) direct into SOUT, fills pa-formation latency */   \
      const char* Kp = (const char*)&Ks[S1][0];                               \
      bf16x8 ak = *(const bf16x8*)(Kp + koff[0]);                             \
      SOUT = __builtin_amdgcn_mfma_f32_32x32x16_bf16(ak, aq[0], z16, 0, 0, 0);\
      _Pragma("unroll")                                                       \
      for (int s = 1; s < 4; ++s) {                                           \
        ak = *(const bf16x8*)(Kp + koff[s]);                                  \
        SOUT = __builtin_amdgcn_mfma_f32_32x32x16_bf16(ak, aq[s], SOUT, 0, 0, 0); \
      }                                                                       \
    }                                                                         \
    {  /* PV(t) */                                                            \
      const char* Vp = (const char*)&Vts[S0][0];                              \
      _Pragma("unroll")                                                       \
      for (int m = 0; m < 2; ++m) {                                           \
        bf16x8 v0 = *(const bf16x8*)(Vp + voff[m][0]);                        \
        bf16x8 v1 = *(const bf16x8*)(Vp + voff[m][1]);                        \
        o_acc[m] = __builtin_amdgcn_mfma_f32_32x32x16_bf16(pa0, v0, o_acc[m], 0, 0, 0); \
        o_acc[m] = __builtin_amdgcn_mfma_f32_32x32x16_bf16(pa1, v1, o_acc[m], 0, 0, 0); \
      }                                                                       \
    }                                                                         \
    __builtin_amdgcn_s_setprio(0);                                            \
  } while (0)

  for (int t = 0; t < 28; t += 4) {
    BODY(t + 0, 0, 1, 2, 1, 1, 2, sacc, nsacc);
    BODY(t + 1, 1, 2, 3, 1, 1, 2, nsacc, sacc);
    BODY(t + 2, 2, 3, 0, 1, 1, 2, sacc, nsacc);
    BODY(t + 3, 3, 0, 1, 1, 1, 2, nsacc, sacc);
  }
  BODY(28, 0, 1, 2, 1, 1, 2, sacc, nsacc);
  BODY(29, 1, 2, 3, 1, 1, 2, nsacc, sacc);
  BODY(30, 2, 3, 0, 0, 1, 0, sacc, nsacc);
  BODY(31, 3, 0, 1, 0, 0, 0, nsacc, sacc);
#undef BODY

  // ---- Epilogue: l wave-pair reduce, O wave-pair merge, normalize, store --
  float* Qf = (float*)&Qs[0];                  // l exchange (Q area dead)
  float* Of = (float*)&Ks[0][0];               // partial-O (K area dead)
  unsigned short* Cs = &Vts[0][0];             // 16 KB out bounce (V slots 0,1)
  const int bq = bh >> 4, head = bh & 15;

  float lw = lpart + __shfl_xor(lpart, 32);    // wave's 32-k half, q = lq
  if (lane < 32) Qf[wv * 32 + lane] = lw;
  __syncthreads();

  if (wv >= 4) {                               // dump partials
#pragma unroll
    for (int m = 0; m < 2; ++m)
#pragma unroll
      for (int r = 0; r < 16; ++r) {
        const int ql = (r & 3) + 8 * (r >> 2) + 4 * hf;
        Of[wq * 2048 + ql * 64 + m * 32 + lq] = o_acc[m][r];
      }
  }
  __syncthreads();

  if (wv < 4) {                                // merge + normalize -> Cs
    float linv[16];
#pragma unroll
    for (int r = 0; r < 16; ++r) {
      const int ql = (r & 3) + 8 * (r >> 2) + 4 * hf;
      linv[r] = 1.0f / (Qf[wv * 32 + ql] + Qf[(wv + 4) * 32 + ql]);
    }
#pragma unroll
    for (int m = 0; m < 2; ++m)
#pragma unroll
      for (int r = 0; r < 16; ++r) {
        const int ql = (r & 3) + 8 * (r >> 2) + 4 * hf;
        const float val =
            (o_acc[m][r] + Of[wq * 2048 + ql * 64 + m * 32 + lq]) * linv[r];
        const int row = wq * 32 + ql, d = m * 32 + lq;
        Cs[row * 64 + (((d >> 3) ^ (row & 7)) << 3) + (d & 7)] = f2bf(val);
      }
  }
  __syncthreads();

#pragma unroll
  for (int s = 0; s < 2; ++s) {
    const int u = s * 512 + tid;        // 1024 units: 128 rows x 8 chunks
    const int mr = u >> 3, ch = u & 7;
    const size_t g = ((size_t)(bq * TT + q0 + mr)) * EE + head * DD + ch * 8;
    const int chs = (ch ^ (mr & 7)) << 3;
    *(uint4*)(ctx + g) = *(const uint4*)(Cs + mr * 64 + chs);
  }
}

// ---------------------------------------------------------------------------
extern "C" void kernel_launch(void* const* d_in, const int* in_sizes, int n_in,
                              void* d_out, int out_size, void* d_ws, size_t ws_size,
                              hipStream_t stream) {
  const float* x  = (const float*)d_in[0];
  const float* Wq = (const float*)d_in[1];
  const float* bq = (const float*)d_in[2];
  const float* Wk = (const float*)d_in[3];
  const float* bk = (const float*)d_in[4];
  const float* Wv = (const float*)d_in[5];
  const float* bv = (const float*)d_in[6];
  const float* Wo = (const float*)d_in[7];
  const float* bo = (const float*)d_in[8];

  unsigned short* p = (unsigned short*)d_ws;
  const size_t XN = (size_t)MM * EE;   // 4M
  const size_t WN = (size_t)EE * EE;   // 1M
  unsigned short* x_h    = p;           p += XN;
  unsigned short* Wcat_h = p;           p += 3 * WN;  // Wq||Wk||Wv rows
  unsigned short* Wo_h   = p;           p += WN;
  unsigned short* Qb     = p;           p += XN;
  unsigned short* Kb     = p;           p += XN;
  unsigned short* Vtb    = p;           p += XN;
  unsigned short* ctx_h  = x_h;         // x_h dead after QKV GEMM

  to_bf16<<<8192, 256, 0, stream>>>(x, Wq, Wk, Wv, Wo, x_h, Wcat_h, Wo_h);

  const float qscale = 0.125f * 1.44269504088896f;   // fold log2e for exp2

  gemm_bf16<0><<<dim3(MM / 128, 3 * EE / 128), 256, 0, stream>>>(
      x_h, Wcat_h, bq, bk, bv, Qb, Kb, Vtb, nullptr, qscale);

  flash_mfma<<<dim3((TT / 128) * BB * HH), 512, 0, stream>>>(Qb, Kb, Vtb, ctx_h);

  gemm_bf16<2><<<dim3(MM / 128, EE / 128), 256, 0, stream>>>(
      ctx_h, Wo_h, bo, nullptr, nullptr,
      nullptr, nullptr, nullptr, (float*)d_out, 1.0f);
}

// Round 7
// 190.926 us; speedup vs baseline: 1.0866x; 1.0866x over previous
//
#include <hip/hip_runtime.h>
#include <math.h>

#define BB 2
#define TT 2048
#define EE 1024
#define HH 16
#define DD 64
#define MM (BB*TT)   // 4096
#define KK EE        // 1024

typedef short bf16x8 __attribute__((ext_vector_type(8)));
typedef float f32x4  __attribute__((ext_vector_type(4)));
typedef float f32x16 __attribute__((ext_vector_type(16)));
typedef unsigned int u32x4 __attribute__((ext_vector_type(4)));

// round-to-nearest-even fp32 -> bf16 (as ushort)
__device__ __forceinline__ unsigned short f2bf(float f) {
  unsigned int u = __float_as_uint(f);
  u = (u + 0x7FFFu + ((u >> 16) & 1u)) >> 16;
  return (unsigned short)u;
}

// packed RNE fp32x2 -> bf16x2 (low = lo)
__device__ __forceinline__ unsigned int cvtpk(float lo, float hi) {
  unsigned int r;
  asm("v_cvt_pk_bf16_f32 %0, %1, %2" : "=v"(r) : "v"(lo), "v"(hi));
  return r;
}

// (a,b) -> a = {a_lo, b_lo}, b = {a_hi, b_hi}  (32-lane half swap)
__device__ __forceinline__ void plswap(unsigned int &a, unsigned int &b) {
  asm("v_permlane32_swap_b32 %0, %1" : "+v"(a), "+v"(b));
}

// async global->LDS DMA, 16B per lane, LDS dest = wave-uniform base + lane*16
__device__ __forceinline__ void async16(const void* g, void* l) {
  __builtin_amdgcn_global_load_lds(
      (const __attribute__((address_space(1))) unsigned int*)g,
      (__attribute__((address_space(3))) unsigned int*)l, 16, 0, 0);
}

// ---------------------------------------------------------------------------
// fp32 -> bf16 convert for x and the 4 weight matrices (Wq/Wk/Wv concatenated
// row-wise into one [3072 x 1024] buffer for the fused QKV GEMM).
// ---------------------------------------------------------------------------
__global__ __launch_bounds__(256) void to_bf16(
    const float* __restrict__ x,  const float* __restrict__ wq,
    const float* __restrict__ wk, const float* __restrict__ wv,
    const float* __restrict__ wo,
    unsigned short* __restrict__ xh, unsigned short* __restrict__ wcat,
    unsigned short* __restrict__ woh)
{
  int c = blockIdx.x * 256 + threadIdx.x;
  const float* src; unsigned short* dst; int off;
  if (c < 1048576) { src = x; dst = xh; off = c; }
  else {
    int r = c - 1048576;
    int w = r >> 18;                 // 262144 chunks per W
    off = r & 262143;
    if      (w == 0) { src = wq; dst = wcat; }
    else if (w == 1) { src = wk; dst = wcat + (1 << 20); }
    else if (w == 2) { src = wv; dst = wcat + (2 << 20); }
    else             { src = wo; dst = woh; }
  }
  float4 v = ((const float4*)src)[off];
  ushort4 h;
  h.x = f2bf(v.x); h.y = f2bf(v.y); h.z = f2bf(v.z); h.w = f2bf(v.w);
  ((ushort4*)dst)[off] = h;
}

// ---------------------------------------------------------------------------
// bf16 MFMA GEMM, 512 threads / 8 waves (4m x 2n wave grid, 32-row wave
// tiles; R5 index math kept verbatim). K-loop restructured to the
// flash-verified quad-buffer single-barrier pipeline: body(t) = { stage(t+2)
// -> counted vmcnt -> s_barrier -> compute(t) }, unrolled x4 so slots are
// compile-time. Race-safety: stage(t+2) writes slot (t-2)%4, last read by
// compute(t-2), which every wave finished before barrier(t-1). vmcnt(4) = 2
// in-flight stages x 2 calls/wave; tail drains 2 -> 0. Replaces 2 barriers +
// implicit full vmcnt drain per K-step (measured: both GEMMs ~47us each,
// barrier-bound at K=1024; MODE2 floor is ~10us).
// MODE 0: fused QKV, tile 128x128, N=3072: Q (*qscale) / K -> bf16
//         [b,h,t,d]; V -> bf16 [b,h,d,t]. LDS 64KB -> 2 blocks/CU.
// MODE 2: fp32 out [m,EE], tile 128x64. LDS 48KB -> 3 blocks/CU.
// ---------------------------------------------------------------------------
template<int MODE>
__global__ __launch_bounds__(512) void gemm_bf16(
    const unsigned short* __restrict__ A, const unsigned short* __restrict__ B,
    const float* __restrict__ b0p, const float* __restrict__ b1p,
    const float* __restrict__ b2p,
    unsigned short* __restrict__ oq, unsigned short* __restrict__ ok,
    unsigned short* __restrict__ ov, float* __restrict__ ofp, float qscale)
{
  constexpr int NT = (MODE == 0) ? 128 : 64;   // n-tile
  constexpr int JN = NT / 32;                  // j-frags per wave (4 / 2)
  constexpr int BROWS = NT * 32;               // B-buffer ushorts per slot
  constexpr int TOT = (MODE == 0) ? 16 : 12;   // staging chunks per K-step
  // A slots: 4 x 4096 at 0; B slots: 4 x BROWS at 16384.
  __shared__ unsigned short S[16384 + 4 * BROWS];

  const int tid  = threadIdx.x;
  const int lane = tid & 63;
  const int wv   = tid >> 6;                   // 0..7
  const int col  = lane & 15;
  const int quad = lane >> 4;
  const int wm = (wv & 3) * 32;
  const int wn = (wv >> 2) * (NT / 2);
  const int m0 = blockIdx.x * 128;
  const int n0 = blockIdx.y * NT;

  const int srow = lane >> 2;                                // 16 rows/call
  const int sw16 = (((lane & 3) ^ ((lane >> 2) & 3)) << 3);  // ushort units
  const int fswA = ((quad ^ (col & 3)) << 3);                // frag slot

  auto stage = [&](int kt, int slot) {
#pragma unroll
    for (int s = 0; s < 2; ++s) {
      const int t = wv * 2 + s;
      if (t < TOT) {
        const unsigned short* src; int rb, g0, loff;
        if (t < 8) { src = A; rb = t * 16;       g0 = m0; loff = slot * 4096; }
        else       { src = B; rb = (t - 8) * 16; g0 = n0; loff = 16384 + slot * BROWS; }
        async16(src + (size_t)(g0 + rb + srow) * KK + kt + sw16,
                S + loff + rb * 32);
      }
    }
  };

  f32x4 acc[2][JN];
  const f32x4 z = {0.f, 0.f, 0.f, 0.f};
#pragma unroll
  for (int i = 0; i < 2; ++i)
#pragma unroll
    for (int j = 0; j < JN; ++j) acc[i][j] = z;

  stage(0, 0);
  stage(32, 1);

#define GBODY(T, SL, S2, DOSTAGE, VMC) do {                                   \
    if (DOSTAGE) stage(((T) + 2) * 32, S2);                                   \
    asm volatile("s_waitcnt vmcnt(" #VMC ")" ::: "memory");                   \
    __builtin_amdgcn_sched_barrier(0);                                        \
    __builtin_amdgcn_s_barrier();                                             \
    __builtin_amdgcn_sched_barrier(0);                                        \
    const unsigned short* Asb = S + (SL) * 4096;                              \
    const unsigned short* Bsb = S + 16384 + (SL) * BROWS;                     \
    bf16x8 bfr[JN];                                                           \
    _Pragma("unroll")                                                         \
    for (int j = 0; j < JN; ++j)                                              \
      bfr[j] = *(const bf16x8*)(Bsb + (wn + j * 16 + col) * 32 + fswA);       \
    _Pragma("unroll")                                                         \
    for (int i = 0; i < 2; ++i) {                                             \
      bf16x8 af = *(const bf16x8*)(Asb + (wm + i * 16 + col) * 32 + fswA);    \
      _Pragma("unroll")                                                       \
      for (int j = 0; j < JN; ++j)                                            \
        acc[i][j] = __builtin_amdgcn_mfma_f32_16x16x32_bf16(af, bfr[j], acc[i][j], 0, 0, 0); \
    }                                                                         \
  } while (0)

  for (int t = 0; t < 28; t += 4) {
    GBODY(t + 0, 0, 2, 1, 4);
    GBODY(t + 1, 1, 3, 1, 4);
    GBODY(t + 2, 2, 0, 1, 4);
    GBODY(t + 3, 3, 1, 1, 4);
  }
  GBODY(28, 0, 2, 1, 4);
  GBODY(29, 1, 3, 1, 4);
  GBODY(30, 2, 0, 0, 2);
  GBODY(31, 3, 0, 0, 0);
#undef GBODY

  // Epilogue. C/D: row = quad*4+r, col = lane&15 per 16x16 tile.
  unsigned short* Cs = S;
  if (MODE == 0) {
    __syncthreads();   // all waves done reading slots before Cs alias writes
    const int region = n0 >> 10;   // block-uniform: 0=Q, 1=K, 2=V
    const float* bias = (region == 0) ? b0p : (region == 1) ? b1p : b2p;
    const float scl = (region == 0) ? qscale : 1.0f;
    const int nlbase = n0 & 1023;
    const int h0 = nlbase >> 6;
    const int b = m0 >> 11, t0 = m0 & (TT - 1);
    if (region < 2) {
      // Cs[m][n] (stride 136): scalar bf16 writes, coalesced row reads.
#pragma unroll
      for (int i = 0; i < 2; ++i)
#pragma unroll
        for (int j = 0; j < 4; ++j) {
          const int nt = wn + j * 16 + col;
          const float bs = bias[nlbase + nt];
#pragma unroll
          for (int r = 0; r < 4; ++r) {
            const int mt = wm + i * 16 + quad * 4 + r;
            Cs[mt * 136 + nt] = f2bf((acc[i][j][r] + bs) * scl);
          }
        }
      __syncthreads();
      unsigned short* dst = (region == 0) ? oq : ok;
#pragma unroll
      for (int s = 0; s < 4; ++s) {
        const int u = s * 512 + tid;          // 2048 units: 128m x 2h x 8ch
        const int mt = u >> 4, hs = (u >> 3) & 1, ch = u & 7;
        const size_t g = ((size_t)(b * HH + h0 + hs) * TT + t0 + mt) * DD + ch * 8;
        *(uint4*)(dst + g) = *(const uint4*)(Cs + mt * 136 + hs * 64 + ch * 8);
      }
    } else {
      // V: Cs[n][m] (stride 136): packed b64 writes, coalesced row reads.
#pragma unroll
      for (int i = 0; i < 2; ++i)
#pragma unroll
        for (int j = 0; j < 4; ++j) {
          const int nt = wn + j * 16 + col;
          const float bs = bias[nlbase + nt];
          ushort4 pk;
          pk.x = f2bf(acc[i][j][0] + bs);
          pk.y = f2bf(acc[i][j][1] + bs);
          pk.z = f2bf(acc[i][j][2] + bs);
          pk.w = f2bf(acc[i][j][3] + bs);
          *(ushort4*)(Cs + nt * 136 + wm + i * 16 + quad * 4) = pk;
        }
      __syncthreads();
#pragma unroll
      for (int s = 0; s < 4; ++s) {
        const int u = s * 512 + tid;          // 2048 units: 128n x 16ch(m)
        const int nt = u >> 4, ch = u & 15;
        const int d = nt & 63, hs = nt >> 6;
        const size_t g = ((size_t)(b * HH + h0 + hs) * DD + d) * TT + t0 + ch * 8;
        *(uint4*)(ov + g) = *(const uint4*)(Cs + nt * 136 + ch * 8);
      }
    }
  } else {
#pragma unroll
    for (int i = 0; i < 2; ++i) {
#pragma unroll
      for (int j = 0; j < JN; ++j) {
        const int n = n0 + wn + j * 16 + col;
        const float bs = b0p[n];
#pragma unroll
        for (int r = 0; r < 4; ++r) {
          const int m = m0 + wm + i * 16 + quad * 4 + r;
          ofp[(size_t)m * EE + n] = acc[i][j][r] + bs;
        }
      }
    }
  }
}

// ---------------------------------------------------------------------------
// MFMA flash attention, 512 threads / 8 waves, 32x32x16 MFMA.
// Wave grid: wq = wv&3 owns 32 q-rows, wk2 = wv>>2 owns a 32-k half of each
// 64-k tile (O partials merged in epilogue). Max-free softmax (Q pre-scaled
// by log2e/8, p = 2^s). S computed transposed (A=K, B=Q) so each lane holds
// P for one q-row; PV A-frags formed IN REGISTERS via v_cvt_pk_bf16_f32 +
// v_permlane32_swap_b32 (T12) — no P LDS roundtrip. QK MFMAs accumulate
// DIRECTLY into the alternating sacc/nsacc register set (first MFMA takes
// C = zero). K/V quad-buffered, 2-ahead prefetch, counted vmcnt(2), one
// barrier per tile.
// ---------------------------------------------------------------------------
__global__ __launch_bounds__(512, 4) void flash_mfma(
    const unsigned short* __restrict__ Qb, const unsigned short* __restrict__ Kb,
    const unsigned short* __restrict__ Vtb, unsigned short* __restrict__ ctx)
{
  __shared__ unsigned short Qs[128 * 64];      // 16 KB (lred/linv at epilogue)
  __shared__ unsigned short Ks[4][64 * 64];    // 32 KB quad-buffered
  __shared__ unsigned short Vts[4][64 * 64];   // 32 KB quad-buffered

  const int tid  = threadIdx.x;
  const int lane = tid & 63;
  const int wv   = tid >> 6;                   // 0..7
  const int lq   = lane & 31;                  // q- or k-local index
  const int hf   = lane >> 5;                  // lane half
  const int wq   = wv & 3;                     // q-block 32*wq
  const int wk2  = wv >> 2;                    // k-half 32*wk2
  const int gid  = blockIdx.x;
  const int bh   = gid & 31;                   // XCD = gid%8 = bh%8
  const int q0   = (gid >> 5) * 128;

  const unsigned short* Qg = Qb  + (size_t)bh * TT * DD;
  const unsigned short* Kg = Kb  + (size_t)bh * TT * DD;
  const unsigned short* Vg = Vtb + (size_t)bh * DD * TT;

  const int srow = lane >> 3;                                // 8 rows/call
  const int sw16 = (((lane & 7) ^ ((lane >> 3) & 7)) << 3);  // ushort units

  // ---- staging (waves 0-3: K, waves 4-7: V^T) ----------------------------
  const int rbK = wq * 16;
  const bool isK = (wv < 4);
  const unsigned short* g0 =
      (isK ? Kg + (size_t)(rbK + srow) * DD : Vg + (size_t)(rbK + srow) * TT) + sw16;
  const unsigned short* g1 = g0 + (isK ? 8 * DD : 8 * TT);
  unsigned short* l0 = (isK ? &Ks[0][0] : &Vts[0][0]) + rbK * 64;
  unsigned short* l1 = l0 + 8 * 64;
  const int gstep = isK ? 64 * DD : 64;        // ushorts per k-tile advance

  auto stage_kv = [&](int ti, int slot) {
    const size_t go = (size_t)ti * gstep;
    async16(g0 + go, l0 + slot * 4096);
    async16(g1 + go, l1 + slot * 4096);
  };

  // ---- loop-invariant fragment byte offsets (XOR chunk-swizzled) ---------
  int koff[4], voff[2][2];
#pragma unroll
  for (int s = 0; s < 4; ++s)
    koff[s] = ((wk2 * 32 + lq) * 64 + (((2 * s + hf) ^ (lane & 7)) << 3)) * 2;
#pragma unroll
  for (int m = 0; m < 2; ++m)
#pragma unroll
    for (int sg = 0; sg < 2; ++sg)
      voff[m][sg] = ((m * 32 + lq) * 64 +
                     (((wk2 * 4 + 2 * sg + hf) ^ (lane & 7)) << 3)) * 2;

  // stage Q (128x64) + K/V tiles 0,1
#pragma unroll
  for (int s = 0; s < 2; ++s) {
    const int rb = wv * 16 + s * 8;
    async16(Qg + (size_t)(q0 + rb + srow) * DD + sw16, &Qs[rb * 64]);
  }
  stage_kv(0, 0);
  stage_kv(1, 1);
  __syncthreads();                             // Q + KV0 + KV1 visible

  // hoist Q fragments (B-operand of S^T): Q[q0+wq*32+lq][16s+8hf+i]
  bf16x8 aq[4];
#pragma unroll
  for (int s = 0; s < 4; ++s)
    aq[s] = *(const bf16x8*)(Qs + (wq * 32 + lq) * 64 +
                             (((2 * s + hf) ^ (lane & 7)) << 3));

  const f32x16 z16 = {0.f,0.f,0.f,0.f,0.f,0.f,0.f,0.f,
                      0.f,0.f,0.f,0.f,0.f,0.f,0.f,0.f};
  f32x16 o_acc[2], sacc, nsacc;
  o_acc[0] = z16; o_acc[1] = z16;
  float lpart = 0.f;

  // prologue QK(0): sacc[r] = S^T[k = wk2*32 + (r&3)+8*(r>>2)+4hf][q = lq]
  {
    const char* Kp = (const char*)&Ks[0][0];
    bf16x8 ak = *(const bf16x8*)(Kp + koff[0]);
    sacc = __builtin_amdgcn_mfma_f32_32x32x16_bf16(ak, aq[0], z16, 0, 0, 0);
#pragma unroll
    for (int s = 1; s < 4; ++s) {
      ak = *(const bf16x8*)(Kp + koff[s]);
      sacc = __builtin_amdgcn_mfma_f32_32x32x16_bf16(ak, aq[s], sacc, 0, 0, 0);
    }
  }

#define BODY(T, S0, S1, S2, DOSTAGE, DOQK, VMC, SIN, SOUT) do {               \
    if (DOSTAGE) stage_kv((T) + 2, S2);                                       \
    asm volatile("s_waitcnt vmcnt(" #VMC ")" ::: "memory");                   \
    __builtin_amdgcn_sched_barrier(0);                                        \
    __builtin_amdgcn_s_barrier();                                             \
    __builtin_amdgcn_sched_barrier(0);                                        \
    bf16x8 pa0, pa1;                                                          \
    {  /* softmax + in-register P A-frag (k-local 0..15 of wave's half) */    \
      float e0 = __builtin_amdgcn_exp2f(SIN[0]);                              \
      float e1 = __builtin_amdgcn_exp2f(SIN[1]);                              \
      float e2 = __builtin_amdgcn_exp2f(SIN[2]);                              \
      float e3 = __builtin_amdgcn_exp2f(SIN[3]);                              \
      float e4 = __builtin_amdgcn_exp2f(SIN[4]);                              \
      float e5 = __builtin_amdgcn_exp2f(SIN[5]);                              \
      float e6 = __builtin_amdgcn_exp2f(SIN[6]);                              \
      float e7 = __builtin_amdgcn_exp2f(SIN[7]);                              \
      lpart += ((e0 + e1) + (e2 + e3)) + ((e4 + e5) + (e6 + e7));             \
      unsigned int a0 = cvtpk(e0, e1), b0 = cvtpk(e4, e5);                    \
      unsigned int a1 = cvtpk(e2, e3), b1 = cvtpk(e6, e7);                    \
      plswap(a0, b0); plswap(a1, b1);                                         \
      u32x4 w = {a0, a1, b0, b1};                                             \
      pa0 = __builtin_bit_cast(bf16x8, w);                                    \
    }                                                                         \
    {  /* k-local 16..31 */                                                   \
      float e0 = __builtin_amdgcn_exp2f(SIN[8]);                              \
      float e1 = __builtin_amdgcn_exp2f(SIN[9]);                              \
      float e2 = __builtin_amdgcn_exp2f(SIN[10]);                             \
      float e3 = __builtin_amdgcn_exp2f(SIN[11]);                             \
      float e4 = __builtin_amdgcn_exp2f(SIN[12]);                             \
      float e5 = __builtin_amdgcn_exp2f(SIN[13]);                             \
      float e6 = __builtin_amdgcn_exp2f(SIN[14]);                             \
      float e7 = __builtin_amdgcn_exp2f(SIN[15]);                             \
      lpart += ((e0 + e1) + (e2 + e3)) + ((e4 + e5) + (e6 + e7));             \
      unsigned int a0 = cvtpk(e0, e1), b0 = cvtpk(e4, e5);                    \
      unsigned int a1 = cvtpk(e2, e3), b1 = cvtpk(e6, e7);                    \
      plswap(a0, b0); plswap(a1, b1);                                         \
      u32x4 w = {a0, a1, b0, b1};                                             \
      pa1 = __builtin_bit_cast(bf16x8, w);                                    \
    }                                                                         \
    __builtin_amdgcn_s_setprio(1);                                            \
    if (DOQK) {  /* QK(t+1) direct into SOUT, fills pa-formation latency */   \
      const char* Kp = (const char*)&Ks[S1][0];                               \
      bf16x8 ak = *(const bf16x8*)(Kp + koff[0]);                             \
      SOUT = __builtin_amdgcn_mfma_f32_32x32x16_bf16(ak, aq[0], z16, 0, 0, 0);\
      _Pragma("unroll")                                                       \
      for (int s = 1; s < 4; ++s) {                                           \
        ak = *(const bf16x8*)(Kp + koff[s]);                                  \
        SOUT = __builtin_amdgcn_mfma_f32_32x32x16_bf16(ak, aq[s], SOUT, 0, 0, 0); \
      }                                                                       \
    }                                                                         \
    {  /* PV(t) */                                                            \
      const char* Vp = (const char*)&Vts[S0][0];                              \
      _Pragma("unroll")                                                       \
      for (int m = 0; m < 2; ++m) {                                           \
        bf16x8 v0 = *(const bf16x8*)(Vp + voff[m][0]);                        \
        bf16x8 v1 = *(const bf16x8*)(Vp + voff[m][1]);                        \
        o_acc[m] = __builtin_amdgcn_mfma_f32_32x32x16_bf16(pa0, v0, o_acc[m], 0, 0, 0); \
        o_acc[m] = __builtin_amdgcn_mfma_f32_32x32x16_bf16(pa1, v1, o_acc[m], 0, 0, 0); \
      }                                                                       \
    }                                                                         \
    __builtin_amdgcn_s_setprio(0);                                            \
  } while (0)

  for (int t = 0; t < 28; t += 4) {
    BODY(t + 0, 0, 1, 2, 1, 1, 2, sacc, nsacc);
    BODY(t + 1, 1, 2, 3, 1, 1, 2, nsacc, sacc);
    BODY(t + 2, 2, 3, 0, 1, 1, 2, sacc, nsacc);
    BODY(t + 3, 3, 0, 1, 1, 1, 2, nsacc, sacc);
  }
  BODY(28, 0, 1, 2, 1, 1, 2, sacc, nsacc);
  BODY(29, 1, 2, 3, 1, 1, 2, nsacc, sacc);
  BODY(30, 2, 3, 0, 0, 1, 0, sacc, nsacc);
  BODY(31, 3, 0, 1, 0, 0, 0, nsacc, sacc);
#undef BODY

  // ---- Epilogue: l wave-pair reduce, O wave-pair merge, normalize, store --
  float* Qf = (float*)&Qs[0];                  // l exchange (Q area dead)
  float* Of = (float*)&Ks[0][0];               // partial-O (K area dead)
  unsigned short* Cs = &Vts[0][0];             // 16 KB out bounce (V slots 0,1)
  const int bq = bh >> 4, head = bh & 15;

  float lw = lpart + __shfl_xor(lpart, 32);    // wave's 32-k half, q = lq
  if (lane < 32) Qf[wv * 32 + lane] = lw;
  __syncthreads();

  if (wv >= 4) {                               // dump partials
#pragma unroll
    for (int m = 0; m < 2; ++m)
#pragma unroll
      for (int r = 0; r < 16; ++r) {
        const int ql = (r & 3) + 8 * (r >> 2) + 4 * hf;
        Of[wq * 2048 + ql * 64 + m * 32 + lq] = o_acc[m][r];
      }
  }
  __syncthreads();

  if (wv < 4) {                                // merge + normalize -> Cs
    float linv[16];
#pragma unroll
    for (int r = 0; r < 16; ++r) {
      const int ql = (r & 3) + 8 * (r >> 2) + 4 * hf;
      linv[r] = 1.0f / (Qf[wv * 32 + ql] + Qf[(wv + 4) * 32 + ql]);
    }
#pragma unroll
    for (int m = 0; m < 2; ++m)
#pragma unroll
      for (int r = 0; r < 16; ++r) {
        const int ql = (r & 3) + 8 * (r >> 2) + 4 * hf;
        const float val =
            (o_acc[m][r] + Of[wq * 2048 + ql * 64 + m * 32 + lq]) * linv[r];
        const int row = wq * 32 + ql, d = m * 32 + lq;
        Cs[row * 64 + (((d >> 3) ^ (row & 7)) << 3) + (d & 7)] = f2bf(val);
      }
  }
  __syncthreads();

#pragma unroll
  for (int s = 0; s < 2; ++s) {
    const int u = s * 512 + tid;        // 1024 units: 128 rows x 8 chunks
    const int mr = u >> 3, ch = u & 7;
    const size_t g = ((size_t)(bq * TT + q0 + mr)) * EE + head * DD + ch * 8;
    const int chs = (ch ^ (mr & 7)) << 3;
    *(uint4*)(ctx + g) = *(const uint4*)(Cs + mr * 64 + chs);
  }
}

// ---------------------------------------------------------------------------
extern "C" void kernel_launch(void* const* d_in, const int* in_sizes, int n_in,
                              void* d_out, int out_size, void* d_ws, size_t ws_size,
                              hipStream_t stream) {
  const float* x  = (const float*)d_in[0];
  const float* Wq = (const float*)d_in[1];
  const float* bq = (const float*)d_in[2];
  const float* Wk = (const float*)d_in[3];
  const float* bk = (const float*)d_in[4];
  const float* Wv = (const float*)d_in[5];
  const float* bv = (const float*)d_in[6];
  const float* Wo = (const float*)d_in[7];
  const float* bo = (const float*)d_in[8];

  unsigned short* p = (unsigned short*)d_ws;
  const size_t XN = (size_t)MM * EE;   // 4M
  const size_t WN = (size_t)EE * EE;   // 1M
  unsigned short* x_h    = p;           p += XN;
  unsigned short* Wcat_h = p;           p += 3 * WN;  // Wq||Wk||Wv rows
  unsigned short* Wo_h   = p;           p += WN;
  unsigned short* Qb     = p;           p += XN;
  unsigned short* Kb     = p;           p += XN;
  unsigned short* Vtb    = p;           p += XN;
  unsigned short* ctx_h  = x_h;         // x_h dead after QKV GEMM

  to_bf16<<<8192, 256, 0, stream>>>(x, Wq, Wk, Wv, Wo, x_h, Wcat_h, Wo_h);

  const float qscale = 0.125f * 1.44269504088896f;   // fold log2e for exp2

  gemm_bf16<0><<<dim3(MM / 128, 3 * EE / 128), 512, 0, stream>>>(
      x_h, Wcat_h, bq, bk, bv, Qb, Kb, Vtb, nullptr, qscale);

  flash_mfma<<<dim3((TT / 128) * BB * HH), 512, 0, stream>>>(Qb, Kb, Vtb, ctx_h);

  gemm_bf16<2><<<dim3(MM / 128, EE / 64), 512, 0, stream>>>(
      ctx_h, Wo_h, bo, nullptr, nullptr,
      nullptr, nullptr, nullptr, (float*)d_out, 1.0f);
}

// Round 8
// 183.396 us; speedup vs baseline: 1.1312x; 1.0411x over previous
//
#include <hip/hip_runtime.h>
#include <math.h>

#define BB 2
#define TT 2048
#define EE 1024
#define HH 16
#define DD 64
#define MM (BB*TT)   // 4096
#define KK EE        // 1024

typedef short bf16x8 __attribute__((ext_vector_type(8)));
typedef float f32x4  __attribute__((ext_vector_type(4)));
typedef float f32x16 __attribute__((ext_vector_type(16)));
typedef unsigned int u32x4 __attribute__((ext_vector_type(4)));

// round-to-nearest-even fp32 -> bf16 (as ushort)
__device__ __forceinline__ unsigned short f2bf(float f) {
  unsigned int u = __float_as_uint(f);
  u = (u + 0x7FFFu + ((u >> 16) & 1u)) >> 16;
  return (unsigned short)u;
}

// packed RNE fp32x2 -> bf16x2 (low = lo)
__device__ __forceinline__ unsigned int cvtpk(float lo, float hi) {
  unsigned int r;
  asm("v_cvt_pk_bf16_f32 %0, %1, %2" : "=v"(r) : "v"(lo), "v"(hi));
  return r;
}

// (a,b) -> a = {a_lo, b_lo}, b = {a_hi, b_hi}  (32-lane half swap)
__device__ __forceinline__ void plswap(unsigned int &a, unsigned int &b) {
  asm("v_permlane32_swap_b32 %0, %1" : "+v"(a), "+v"(b));
}

// async global->LDS DMA, 16B per lane, LDS dest = wave-uniform base + lane*16
__device__ __forceinline__ void async16(const void* g, void* l) {
  __builtin_amdgcn_global_load_lds(
      (const __attribute__((address_space(1))) unsigned int*)g,
      (__attribute__((address_space(3))) unsigned int*)l, 16, 0, 0);
}

// ---------------------------------------------------------------------------
// fp32 -> bf16 convert for x and the 4 weight matrices (Wq/Wk/Wv concatenated
// row-wise into one [3072 x 1024] buffer for the fused QKV GEMM).
// ---------------------------------------------------------------------------
__global__ __launch_bounds__(256) void to_bf16(
    const float* __restrict__ x,  const float* __restrict__ wq,
    const float* __restrict__ wk, const float* __restrict__ wv,
    const float* __restrict__ wo,
    unsigned short* __restrict__ xh, unsigned short* __restrict__ wcat,
    unsigned short* __restrict__ woh)
{
  int c = blockIdx.x * 256 + threadIdx.x;
  const float* src; unsigned short* dst; int off;
  if (c < 1048576) { src = x; dst = xh; off = c; }
  else {
    int r = c - 1048576;
    int w = r >> 18;                 // 262144 chunks per W
    off = r & 262143;
    if      (w == 0) { src = wq; dst = wcat; }
    else if (w == 1) { src = wk; dst = wcat + (1 << 20); }
    else if (w == 2) { src = wv; dst = wcat + (2 << 20); }
    else             { src = wo; dst = woh; }
  }
  float4 v = ((const float4*)src)[off];
  ushort4 h;
  h.x = f2bf(v.x); h.y = f2bf(v.y); h.z = f2bf(v.z); h.w = f2bf(v.w);
  ((ushort4*)dst)[off] = h;
}

// ---------------------------------------------------------------------------
// bf16 MFMA GEMM, 512 threads / 8 waves (4m x 2n wave grid, 32-row wave
// tiles). K-loop: TRIPLE-buffered single-barrier pipeline, 1-ahead staging:
// body(t) = { stage(t+1) -> vmcnt(2) -> s_barrier -> compute(t) }. Race-
// safety: stage(t+1) writes slot (t+1)%3 = (t-2)%3, last read by
// compute(t-2); every wave passed barrier(t-1), reachable only after
// finishing compute(t-2). vmcnt(2) = the 2 calls of stage(t+1) may remain
// in flight; stage(t) (own contribution) is confirmed complete, barrier
// publishes cross-wave.
// 3 slots (was 4): MODE0 LDS 64->48 KB -> 3 blocks/CU (grid 768 = 3/CU,
// previously LDS-capped at 2 -> 33% occupancy loss). launch_bounds(512,6)
// keeps VGPR within the 6-waves/SIMD budget.
// MODE 0: fused QKV, tile 128x128, N=3072: Q (*qscale) / K -> bf16
//         [b,h,t,d]; V -> bf16 [b,h,d,t].
// MODE 2: fp32 out [m,EE], tile 128x64 (grid-capped at 2/CU either way).
// ---------------------------------------------------------------------------
template<int MODE>
__global__ __launch_bounds__(512, 6) void gemm_bf16(
    const unsigned short* __restrict__ A, const unsigned short* __restrict__ B,
    const float* __restrict__ b0p, const float* __restrict__ b1p,
    const float* __restrict__ b2p,
    unsigned short* __restrict__ oq, unsigned short* __restrict__ ok,
    unsigned short* __restrict__ ov, float* __restrict__ ofp, float qscale)
{
  constexpr int NT = (MODE == 0) ? 128 : 64;   // n-tile
  constexpr int JN = NT / 32;                  // j-frags per wave (4 / 2)
  constexpr int BROWS = NT * 32;               // B-buffer ushorts per slot
  constexpr int TOT = (MODE == 0) ? 16 : 12;   // staging chunks per K-step
  // A slots: 3 x 4096 at 0; B slots: 3 x BROWS at 12288.
  __shared__ unsigned short S[12288 + 3 * BROWS];

  const int tid  = threadIdx.x;
  const int lane = tid & 63;
  const int wv   = tid >> 6;                   // 0..7
  const int col  = lane & 15;
  const int quad = lane >> 4;
  const int wm = (wv & 3) * 32;
  const int wn = (wv >> 2) * (NT / 2);
  const int m0 = blockIdx.x * 128;
  const int n0 = blockIdx.y * NT;

  const int srow = lane >> 2;                                // 16 rows/call
  const int sw16 = (((lane & 3) ^ ((lane >> 2) & 3)) << 3);  // ushort units
  const int fswA = ((quad ^ (col & 3)) << 3);                // frag slot

  auto stage = [&](int kt, int slot) {
#pragma unroll
    for (int s = 0; s < 2; ++s) {
      const int t = wv * 2 + s;
      if (t < TOT) {
        const unsigned short* src; int rb, g0, loff;
        if (t < 8) { src = A; rb = t * 16;       g0 = m0; loff = slot * 4096; }
        else       { src = B; rb = (t - 8) * 16; g0 = n0; loff = 12288 + slot * BROWS; }
        async16(src + (size_t)(g0 + rb + srow) * KK + kt + sw16,
                S + loff + rb * 32);
      }
    }
  };

  f32x4 acc[2][JN];
  const f32x4 z = {0.f, 0.f, 0.f, 0.f};
#pragma unroll
  for (int i = 0; i < 2; ++i)
#pragma unroll
    for (int j = 0; j < JN; ++j) acc[i][j] = z;

  stage(0, 0);

#define GBODY(T, SL, S2, DOSTAGE, VMC) do {                                   \
    if (DOSTAGE) stage(((T) + 1) * 32, S2);                                   \
    asm volatile("s_waitcnt vmcnt(" #VMC ")" ::: "memory");                   \
    __builtin_amdgcn_sched_barrier(0);                                        \
    __builtin_amdgcn_s_barrier();                                             \
    __builtin_amdgcn_sched_barrier(0);                                        \
    const unsigned short* Asb = S + (SL) * 4096;                              \
    const unsigned short* Bsb = S + 12288 + (SL) * BROWS;                     \
    bf16x8 bfr[JN];                                                           \
    _Pragma("unroll")                                                         \
    for (int j = 0; j < JN; ++j)                                              \
      bfr[j] = *(const bf16x8*)(Bsb + (wn + j * 16 + col) * 32 + fswA);       \
    _Pragma("unroll")                                                         \
    for (int i = 0; i < 2; ++i) {                                             \
      bf16x8 af = *(const bf16x8*)(Asb + (wm + i * 16 + col) * 32 + fswA);    \
      _Pragma("unroll")                                                       \
      for (int j = 0; j < JN; ++j)                                            \
        acc[i][j] = __builtin_amdgcn_mfma_f32_16x16x32_bf16(af, bfr[j], acc[i][j], 0, 0, 0); \
    }                                                                         \
  } while (0)

  for (int t = 0; t < 30; t += 3) {
    GBODY(t + 0, 0, 1, 1, 2);
    GBODY(t + 1, 1, 2, 1, 2);
    GBODY(t + 2, 2, 0, 1, 2);
  }
  GBODY(30, 0, 1, 1, 2);
  GBODY(31, 1, 0, 0, 0);
#undef GBODY

  // Epilogue. C/D: row = quad*4+r, col = lane&15 per 16x16 tile.
  unsigned short* Cs = S;
  if (MODE == 0) {
    __syncthreads();   // all waves done reading slots before Cs alias writes
    const int region = n0 >> 10;   // block-uniform: 0=Q, 1=K, 2=V
    const float* bias = (region == 0) ? b0p : (region == 1) ? b1p : b2p;
    const float scl = (region == 0) ? qscale : 1.0f;
    const int nlbase = n0 & 1023;
    const int h0 = nlbase >> 6;
    const int b = m0 >> 11, t0 = m0 & (TT - 1);
    if (region < 2) {
      // Cs[m][n] (stride 136): scalar bf16 writes, coalesced row reads.
#pragma unroll
      for (int i = 0; i < 2; ++i)
#pragma unroll
        for (int j = 0; j < 4; ++j) {
          const int nt = wn + j * 16 + col;
          const float bs = bias[nlbase + nt];
#pragma unroll
          for (int r = 0; r < 4; ++r) {
            const int mt = wm + i * 16 + quad * 4 + r;
            Cs[mt * 136 + nt] = f2bf((acc[i][j][r] + bs) * scl);
          }
        }
      __syncthreads();
      unsigned short* dst = (region == 0) ? oq : ok;
#pragma unroll
      for (int s = 0; s < 4; ++s) {
        const int u = s * 512 + tid;          // 2048 units: 128m x 2h x 8ch
        const int mt = u >> 4, hs = (u >> 3) & 1, ch = u & 7;
        const size_t g = ((size_t)(b * HH + h0 + hs) * TT + t0 + mt) * DD + ch * 8;
        *(uint4*)(dst + g) = *(const uint4*)(Cs + mt * 136 + hs * 64 + ch * 8);
      }
    } else {
      // V: Cs[n][m] (stride 136): packed b64 writes, coalesced row reads.
#pragma unroll
      for (int i = 0; i < 2; ++i)
#pragma unroll
        for (int j = 0; j < 4; ++j) {
          const int nt = wn + j * 16 + col;
          const float bs = bias[nlbase + nt];
          ushort4 pk;
          pk.x = f2bf(acc[i][j][0] + bs);
          pk.y = f2bf(acc[i][j][1] + bs);
          pk.z = f2bf(acc[i][j][2] + bs);
          pk.w = f2bf(acc[i][j][3] + bs);
          *(ushort4*)(Cs + nt * 136 + wm + i * 16 + quad * 4) = pk;
        }
      __syncthreads();
#pragma unroll
      for (int s = 0; s < 4; ++s) {
        const int u = s * 512 + tid;          // 2048 units: 128n x 16ch(m)
        const int nt = u >> 4, ch = u & 15;
        const int d = nt & 63, hs = nt >> 6;
        const size_t g = ((size_t)(b * HH + h0 + hs) * DD + d) * TT + t0 + ch * 8;
        *(uint4*)(ov + g) = *(const uint4*)(Cs + nt * 136 + ch * 8);
      }
    }
  } else {
#pragma unroll
    for (int i = 0; i < 2; ++i) {
#pragma unroll
      for (int j = 0; j < JN; ++j) {
        const int n = n0 + wn + j * 16 + col;
        const float bs = b0p[n];
#pragma unroll
        for (int r = 0; r < 4; ++r) {
          const int m = m0 + wm + i * 16 + quad * 4 + r;
          ofp[(size_t)m * EE + n] = acc[i][j][r] + bs;
        }
      }
    }
  }
}

// ---------------------------------------------------------------------------
// MFMA flash attention, 512 threads / 8 waves, 32x32x16 MFMA.
// (Byte-identical to prev round — control for GEMM-occupancy attribution.)
// Wave grid: wq = wv&3 owns 32 q-rows, wk2 = wv>>2 owns a 32-k half of each
// 64-k tile (O partials merged in epilogue). Max-free softmax (Q pre-scaled
// by log2e/8, p = 2^s). S computed transposed (A=K, B=Q) so each lane holds
// P for one q-row; PV A-frags formed IN REGISTERS via v_cvt_pk_bf16_f32 +
// v_permlane32_swap_b32 (T12) — no P LDS roundtrip. QK MFMAs accumulate
// DIRECTLY into the alternating sacc/nsacc register set (first MFMA takes
// C = zero). K/V quad-buffered, 2-ahead prefetch, counted vmcnt(2), one
// barrier per tile. Grid = 512 blocks = 2 blocks/CU (grid-capped).
// ---------------------------------------------------------------------------
__global__ __launch_bounds__(512, 4) void flash_mfma(
    const unsigned short* __restrict__ Qb, const unsigned short* __restrict__ Kb,
    const unsigned short* __restrict__ Vtb, unsigned short* __restrict__ ctx)
{
  __shared__ unsigned short Qs[128 * 64];      // 16 KB (lred/linv at epilogue)
  __shared__ unsigned short Ks[4][64 * 64];    // 32 KB quad-buffered
  __shared__ unsigned short Vts[4][64 * 64];   // 32 KB quad-buffered

  const int tid  = threadIdx.x;
  const int lane = tid & 63;
  const int wv   = tid >> 6;                   // 0..7
  const int lq   = lane & 31;                  // q- or k-local index
  const int hf   = lane >> 5;                  // lane half
  const int wq   = wv & 3;                     // q-block 32*wq
  const int wk2  = wv >> 2;                    // k-half 32*wk2
  const int gid  = blockIdx.x;
  const int bh   = gid & 31;                   // XCD = gid%8 = bh%8
  const int q0   = (gid >> 5) * 128;

  const unsigned short* Qg = Qb  + (size_t)bh * TT * DD;
  const unsigned short* Kg = Kb  + (size_t)bh * TT * DD;
  const unsigned short* Vg = Vtb + (size_t)bh * DD * TT;

  const int srow = lane >> 3;                                // 8 rows/call
  const int sw16 = (((lane & 7) ^ ((lane >> 3) & 7)) << 3);  // ushort units

  // ---- staging (waves 0-3: K, waves 4-7: V^T) ----------------------------
  const int rbK = wq * 16;
  const bool isK = (wv < 4);
  const unsigned short* g0 =
      (isK ? Kg + (size_t)(rbK + srow) * DD : Vg + (size_t)(rbK + srow) * TT) + sw16;
  const unsigned short* g1 = g0 + (isK ? 8 * DD : 8 * TT);
  unsigned short* l0 = (isK ? &Ks[0][0] : &Vts[0][0]) + rbK * 64;
  unsigned short* l1 = l0 + 8 * 64;
  const int gstep = isK ? 64 * DD : 64;        // ushorts per k-tile advance

  auto stage_kv = [&](int ti, int slot) {
    const size_t go = (size_t)ti * gstep;
    async16(g0 + go, l0 + slot * 4096);
    async16(g1 + go, l1 + slot * 4096);
  };

  // ---- loop-invariant fragment byte offsets (XOR chunk-swizzled) ---------
  int koff[4], voff[2][2];
#pragma unroll
  for (int s = 0; s < 4; ++s)
    koff[s] = ((wk2 * 32 + lq) * 64 + (((2 * s + hf) ^ (lane & 7)) << 3)) * 2;
#pragma unroll
  for (int m = 0; m < 2; ++m)
#pragma unroll
    for (int sg = 0; sg < 2; ++sg)
      voff[m][sg] = ((m * 32 + lq) * 64 +
                     (((wk2 * 4 + 2 * sg + hf) ^ (lane & 7)) << 3)) * 2;

  // stage Q (128x64) + K/V tiles 0,1
#pragma unroll
  for (int s = 0; s < 2; ++s) {
    const int rb = wv * 16 + s * 8;
    async16(Qg + (size_t)(q0 + rb + srow) * DD + sw16, &Qs[rb * 64]);
  }
  stage_kv(0, 0);
  stage_kv(1, 1);
  __syncthreads();                             // Q + KV0 + KV1 visible

  // hoist Q fragments (B-operand of S^T): Q[q0+wq*32+lq][16s+8hf+i]
  bf16x8 aq[4];
#pragma unroll
  for (int s = 0; s < 4; ++s)
    aq[s] = *(const bf16x8*)(Qs + (wq * 32 + lq) * 64 +
                             (((2 * s + hf) ^ (lane & 7)) << 3));

  const f32x16 z16 = {0.f,0.f,0.f,0.f,0.f,0.f,0.f,0.f,
                      0.f,0.f,0.f,0.f,0.f,0.f,0.f,0.f};
  f32x16 o_acc[2], sacc, nsacc;
  o_acc[0] = z16; o_acc[1] = z16;
  float lpart = 0.f;

  // prologue QK(0): sacc[r] = S^T[k = wk2*32 + (r&3)+8*(r>>2)+4hf][q = lq]
  {
    const char* Kp = (const char*)&Ks[0][0];
    bf16x8 ak = *(const bf16x8*)(Kp + koff[0]);
    sacc = __builtin_amdgcn_mfma_f32_32x32x16_bf16(ak, aq[0], z16, 0, 0, 0);
#pragma unroll
    for (int s = 1; s < 4; ++s) {
      ak = *(const bf16x8*)(Kp + koff[s]);
      sacc = __builtin_amdgcn_mfma_f32_32x32x16_bf16(ak, aq[s], sacc, 0, 0, 0);
    }
  }

#define BODY(T, S0, S1, S2, DOSTAGE, DOQK, VMC, SIN, SOUT) do {               \
    if (DOSTAGE) stage_kv((T) + 2, S2);                                       \
    asm volatile("s_waitcnt vmcnt(" #VMC ")" ::: "memory");                   \
    __builtin_amdgcn_sched_barrier(0);                                        \
    __builtin_amdgcn_s_barrier();                                             \
    __builtin_amdgcn_sched_barrier(0);                                        \
    bf16x8 pa0, pa1;                                                          \
    {  /* softmax + in-register P A-frag (k-local 0..15 of wave's half) */    \
      float e0 = __builtin_amdgcn_exp2f(SIN[0]);                              \
      float e1 = __builtin_amdgcn_exp2f(SIN[1]);                              \
      float e2 = __builtin_amdgcn_exp2f(SIN[2]);                              \
      float e3 = __builtin_amdgcn_exp2f(SIN[3]);                              \
      float e4 = __builtin_amdgcn_exp2f(SIN[4]);                              \
      float e5 = __builtin_amdgcn_exp2f(SIN[5]);                              \
      float e6 = __builtin_amdgcn_exp2f(SIN[6]);                              \
      float e7 = __builtin_amdgcn_exp2f(SIN[7]);                              \
      lpart += ((e0 + e1) + (e2 + e3)) + ((e4 + e5) + (e6 + e7));             \
      unsigned int a0 = cvtpk(e0, e1), b0 = cvtpk(e4, e5);                    \
      unsigned int a1 = cvtpk(e2, e3), b1 = cvtpk(e6, e7);                    \
      plswap(a0, b0); plswap(a1, b1);                                         \
      u32x4 w = {a0, a1, b0, b1};                                             \
      pa0 = __builtin_bit_cast(bf16x8, w);                                    \
    }                                                                         \
    {  /* k-local 16..31 */                                                   \
      float e0 = __builtin_amdgcn_exp2f(SIN[8]);                              \
      float e1 = __builtin_amdgcn_exp2f(SIN[9]);                              \
      float e2 = __builtin_amdgcn_exp2f(SIN[10]);                             \
      float e3 = __builtin_amdgcn_exp2f(SIN[11]);                             \
      float e4 = __builtin_amdgcn_exp2f(SIN[12]);                             \
      float e5 = __builtin_amdgcn_exp2f(SIN[13]);                             \
      float e6 = __builtin_amdgcn_exp2f(SIN[14]);                             \
      float e7 = __builtin_amdgcn_exp2f(SIN[15]);                             \
      lpart += ((e0 + e1) + (e2 + e3)) + ((e4 + e5) + (e6 + e7));             \
      unsigned int a0 = cvtpk(e0, e1), b0 = cvtpk(e4, e5);                    \
      unsigned int a1 = cvtpk(e2, e3), b1 = cvtpk(e6, e7);                    \
      plswap(a0, b0); plswap(a1, b1);                                         \
      u32x4 w = {a0, a1, b0, b1};                                             \
      pa1 = __builtin_bit_cast(bf16x8, w);                                    \
    }                                                                         \
    __builtin_amdgcn_s_setprio(1);                                            \
    if (DOQK) {  /* QK(t+1) direct into SOUT, fills pa-formation latency */   \
      const char* Kp = (const char*)&Ks[S1][0];                               \
      bf16x8 ak = *(const bf16x8*)(Kp + koff[0]);                             \
      SOUT = __builtin_amdgcn_mfma_f32_32x32x16_bf16(ak, aq[0], z16, 0, 0, 0);\
      _Pragma("unroll")                                                       \
      for (int s = 1; s < 4; ++s) {                                           \
        ak = *(const bf16x8*)(Kp + koff[s]);                                  \
        SOUT = __builtin_amdgcn_mfma_f32_32x32x16_bf16(ak, aq[s], SOUT, 0, 0, 0); \
      }                                                                       \
    }                                                                         \
    {  /* PV(t) */                                                            \
      const char* Vp = (const char*)&Vts[S0][0];                              \
      _Pragma("unroll")                                                       \
      for (int m = 0; m < 2; ++m) {                                           \
        bf16x8 v0 = *(const bf16x8*)(Vp + voff[m][0]);                        \
        bf16x8 v1 = *(const bf16x8*)(Vp + voff[m][1]);                        \
        o_acc[m] = __builtin_amdgcn_mfma_f32_32x32x16_bf16(pa0, v0, o_acc[m], 0, 0, 0); \
        o_acc[m] = __builtin_amdgcn_mfma_f32_32x32x16_bf16(pa1, v1, o_acc[m], 0, 0, 0); \
      }                                                                       \
    }                                                                         \
    __builtin_amdgcn_s_setprio(0);                                            \
  } while (0)

  for (int t = 0; t < 28; t += 4) {
    BODY(t + 0, 0, 1, 2, 1, 1, 2, sacc, nsacc);
    BODY(t + 1, 1, 2, 3, 1, 1, 2, nsacc, sacc);
    BODY(t + 2, 2, 3, 0, 1, 1, 2, sacc, nsacc);
    BODY(t + 3, 3, 0, 1, 1, 1, 2, nsacc, sacc);
  }
  BODY(28, 0, 1, 2, 1, 1, 2, sacc, nsacc);
  BODY(29, 1, 2, 3, 1, 1, 2, nsacc, sacc);
  BODY(30, 2, 3, 0, 0, 1, 0, sacc, nsacc);
  BODY(31, 3, 0, 1, 0, 0, 0, nsacc, sacc);
#undef BODY

  // ---- Epilogue: l wave-pair reduce, O wave-pair merge, normalize, store --
  float* Qf = (float*)&Qs[0];                  // l exchange (Q area dead)
  float* Of = (float*)&Ks[0][0];               // partial-O (K area dead)
  unsigned short* Cs = &Vts[0][0];             // 16 KB out bounce (V slots 0,1)
  const int bq = bh >> 4, head = bh & 15;

  float lw = lpart + __shfl_xor(lpart, 32);    // wave's 32-k half, q = lq
  if (lane < 32) Qf[wv * 32 + lane] = lw;
  __syncthreads();

  if (wv >= 4) {                               // dump partials
#pragma unroll
    for (int m = 0; m < 2; ++m)
#pragma unroll
      for (int r = 0; r < 16; ++r) {
        const int ql = (r & 3) + 8 * (r >> 2) + 4 * hf;
        Of[wq * 2048 + ql * 64 + m * 32 + lq] = o_acc[m][r];
      }
  }
  __syncthreads();

  if (wv < 4) {                                // merge + normalize -> Cs
    float linv[16];
#pragma unroll
    for (int r = 0; r < 16; ++r) {
      const int ql = (r & 3) + 8 * (r >> 2) + 4 * hf;
      linv[r] = 1.0f / (Qf[wv * 32 + ql] + Qf[(wv + 4) * 32 + ql]);
    }
#pragma unroll
    for (int m = 0; m < 2; ++m)
#pragma unroll
      for (int r = 0; r < 16; ++r) {
        const int ql = (r & 3) + 8 * (r >> 2) + 4 * hf;
        const float val =
            (o_acc[m][r] + Of[wq * 2048 + ql * 64 + m * 32 + lq]) * linv[r];
        const int row = wq * 32 + ql, d = m * 32 + lq;
        Cs[row * 64 + (((d >> 3) ^ (row & 7)) << 3) + (d & 7)] = f2bf(val);
      }
  }
  __syncthreads();

#pragma unroll
  for (int s = 0; s < 2; ++s) {
    const int u = s * 512 + tid;        // 1024 units: 128 rows x 8 chunks
    const int mr = u >> 3, ch = u & 7;
    const size_t g = ((size_t)(bq * TT + q0 + mr)) * EE + head * DD + ch * 8;
    const int chs = (ch ^ (mr & 7)) << 3;
    *(uint4*)(ctx + g) = *(const uint4*)(Cs + mr * 64 + chs);
  }
}

// ---------------------------------------------------------------------------
extern "C" void kernel_launch(void* const* d_in, const int* in_sizes, int n_in,
                              void* d_out, int out_size, void* d_ws, size_t ws_size,
                              hipStream_t stream) {
  const float* x  = (const float*)d_in[0];
  const float* Wq = (const float*)d_in[1];
  const float* bq = (const float*)d_in[2];
  const float* Wk = (const float*)d_in[3];
  const float* bk = (const float*)d_in[4];
  const float* Wv = (const float*)d_in[5];
  const float* bv = (const float*)d_in[6];
  const float* Wo = (const float*)d_in[7];
  const float* bo = (const float*)d_in[8];

  unsigned short* p = (unsigned short*)d_ws;
  const size_t XN = (size_t)MM * EE;   // 4M
  const size_t WN = (size_t)EE * EE;   // 1M
  unsigned short* x_h    = p;           p += XN;
  unsigned short* Wcat_h = p;           p += 3 * WN;  // Wq||Wk||Wv rows
  unsigned short* Wo_h   = p;           p += WN;
  unsigned short* Qb     = p;           p += XN;
  unsigned short* Kb     = p;           p += XN;
  unsigned short* Vtb    = p;           p += XN;
  unsigned short* ctx_h  = x_h;         // x_h dead after QKV GEMM

  to_bf16<<<8192, 256, 0, stream>>>(x, Wq, Wk, Wv, Wo, x_h, Wcat_h, Wo_h);

  const float qscale = 0.125f * 1.44269504088896f;   // fold log2e for exp2

  gemm_bf16<0><<<dim3(MM / 128, 3 * EE / 128), 512, 0, stream>>>(
      x_h, Wcat_h, bq, bk, bv, Qb, Kb, Vtb, nullptr, qscale);

  flash_mfma<<<dim3((TT / 128) * BB * HH), 512, 0, stream>>>(Qb, Kb, Vtb, ctx_h);

  gemm_bf16<2><<<dim3(MM / 128, EE / 64), 512, 0, stream>>>(
      ctx_h, Wo_h, bo, nullptr, nullptr,
      nullptr, nullptr, nullptr, (float*)d_out, 1.0f);
}